// Round 11
// baseline (406.615 us; speedup 1.0000x reference)
//
#include <hip/hip_runtime.h>
#include <hip/hip_bf16.h>
#include <hip/hip_fp16.h>
#include <cstdint>

// Problem constants
constexpr int B_   = 64;
constexpr int L_   = 512;
constexpr int G_   = 128;
constexpr int E_   = 65536;
constexpr int RH   = 256;    // NREL*NHID
constexpr int M_   = 2048;   // B*N distinct nodes
constexpr int JA   = 33;     // augmented j (32 + const-1 slot)
constexpr int COLS = RH * JA;   // 8448
constexpr int NREP = 16;     // LN-stat accumulator replicas (atomic decontention)

typedef _Float16 v2h __attribute__((ext_vector_type(2)));
typedef _Float16 v8h __attribute__((ext_vector_type(8)));
typedef float    v4f __attribute__((ext_vector_type(4)));
typedef union { uint4 u4; v8h h8; } cvt8;

#define DEV static __device__ __forceinline__

DEV float sigm(float x) { return 1.f / (1.f + __expf(-x)); }
DEV float tanh_fast(float x) {
    x = fminf(15.f, fmaxf(-15.f, x));
    float e = __expf(2.f * x);
    return (e - 1.f) / (e + 1.f);
}

// ---------------- K_eh: embed + edge histograms + waug build ----------------
// blocks 0..255: embed (4 blocks/batch, lgkm-clean inner loop);
// blocks 256..511: hist; 512..1600: waug (read-coalesced).
// waug layout: waug[i*COLS + j*256 + rh]
__global__ __launch_bounds__(256) void k_eh(const int* __restrict__ seq,
                                            const int* __restrict__ p2g,
                                            const float* __restrict__ emb,
                                            const int* __restrict__ u,
                                            const int* __restrict__ v,
                                            const float* __restrict__ ntlw,
                                            const float* __restrict__ ntlv,
                                            const float* __restrict__ ntlb,
                                            float* __restrict__ xg,
                                            int* __restrict__ cu, int* __restrict__ cv,
                                            float* __restrict__ waug) {
    int blk = blockIdx.x;
    int t   = threadIdx.x;
    if (blk >= 512) {
        int gid = (blk - 512) * 256 + t;      // j-fastest: coalesced ntlw reads
        int i   = gid / COLS;
        int rem = gid - i * COLS;
        int rh  = rem / JA;
        int j   = rem - rh * JA;
        float val;
        if (i < 32) val = (j < 32) ? ntlw[((size_t)rh * 32 + i) * 32 + j] : ntlv[rh * 64 + i];
        else        val = (j < 32) ? ntlv[rh * 64 + 32 + j] : ntlb[rh];
        waug[(size_t)i * COLS + j * 256 + rh] = val;   // scattered, L2-absorbed
        return;
    }
    if (blk >= 256) {
        int n = (blk - 256) * 256 + t;
        atomicAdd(&cu[u[n]], 1);
        atomicAdd(&cv[v[n]], 1);
        return;
    }
    // ---- embed: 4 blocks per batch, each covers 128 sequence positions ----
    __shared__ float xgl[G_ * 64];          // 32 KB partial sums
    __shared__ int sl[128], gld[128];
    int b = blk >> 2, part = blk & 3;
    for (int i = t; i < G_ * 64; i += 256) xgl[i] = 0.f;
    if (t < 128) {
        sl[t]  = seq[b * L_ + part * 128 + t];
        gld[t] = p2g[b * L_ + part * 128 + t];
    }
    __syncthreads();
    int d = t & 63, sub = t >> 6;
#pragma unroll
    for (int gg = 0; gg < 2; gg++) {
        int sv[16], gv[16];
#pragma unroll
        for (int k = 0; k < 16; k++) {       // batch LDS reads first (lgkm group)
            sv[k] = sl[sub * 32 + gg * 16 + k];
            gv[k] = gld[sub * 32 + gg * 16 + k];
        }
#pragma unroll
        for (int k = 0; k < 16; k++)         // then pure-vm loads + ds atomics
            atomicAdd(&xgl[gv[k] * 64 + d], emb[(size_t)sv[k] * 64 + d]);
    }
    __syncthreads();
    for (int i = t; i < G_ * 64; i += 256)   // flush partials (xg pre-zeroed)
        atomicAdd(&xg[(size_t)b * G_ * 64 + i], xgl[i]);
}

// ---------------- K_pre: input-gate GEMM (scalar x broadcast) + scan --------
__global__ __launch_bounds__(256) void k_pre(const float* __restrict__ xg,
                                             const float* __restrict__ wihf,
                                             const float* __restrict__ bihf,
                                             const float* __restrict__ bhhf,
                                             const float* __restrict__ wihb,
                                             const float* __restrict__ bihb,
                                             const float* __restrict__ bhhb,
                                             float* __restrict__ pre,
                                             const int* __restrict__ cu,
                                             int* __restrict__ ustart,
                                             int* __restrict__ ucursor) {
    int blk = blockIdx.x;
    int t   = threadIdx.x;
    if (blk == 512) {
        __shared__ int ps[256];
        int base = t * 8, run = 0;
        int c[8], loc[8];
#pragma unroll
        for (int i = 0; i < 8; i++) c[i] = cu[base + i];
#pragma unroll
        for (int i = 0; i < 8; i++) { loc[i] = run; run += c[i]; }
        ps[t] = run;
        __syncthreads();
        for (int off = 1; off < 256; off <<= 1) {
            int a = (t >= off) ? ps[t - off] : 0;
            __syncthreads();
            ps[t] += a;
            __syncthreads();
        }
        int ex = ps[t] - run;
#pragma unroll
        for (int i = 0; i < 8; i++) { ustart[base + i] = ex + loc[i]; ucursor[base + i] = ex + loc[i]; }
        if (t == 255) ustart[2048] = E_;
        return;
    }
    int dir = blk >> 8;
    const float* wih = dir ? wihb : wihf;
    float bias = dir ? (bihb[t] + bhhb[t]) : (bihf[t] + bhhf[t]);
    int r0 = (blk & 255) * 32;

    float4 wv[16];
#pragma unroll
    for (int c = 0; c < 16; c++) wv[c] = ((const float4*)(wih + t * 64))[c];

#pragma unroll 2
    for (int ml = 0; ml < 32; ml++) {
        const float* xr = xg + (size_t)(r0 + ml) * 64;   // wave-uniform -> s_load
        float acc = bias;
#pragma unroll
        for (int c = 0; c < 16; c++) {
            float x0 = xr[4 * c], x1 = xr[4 * c + 1], x2 = xr[4 * c + 2], x3 = xr[4 * c + 3];
            acc += x0 * wv[c].x + x1 * wv[c].y + x2 * wv[c].z + x3 * wv[c].w;
        }
        pre[((size_t)dir * 8192 + r0 + ml) * 256 + t] = acc;   // gate-major, coalesced
    }
}

// ---------------- K_lstm: merged 128-step recurrence (R6 structure) ---------
// blocks 128..383: edge counting-sort rider.
__global__ __launch_bounds__(256, 1) void k_lstm(const float* __restrict__ pre,
                                                 const float* __restrict__ whh_f,
                                                 const float* __restrict__ whh_b,
                                                 float* __restrict__ hgrp,
                                                 const int* __restrict__ u,
                                                 const int* __restrict__ v,
                                                 int* __restrict__ ucursor,
                                                 int2* __restrict__ eonv) {
    int blk = blockIdx.x;
    int t   = threadIdx.x;
    if (blk >= 128) {
        int n = (blk - 128) * 256 + t;
        int pos = atomicAdd(&ucursor[u[n]], 1);
        eonv[pos] = make_int2(n, v[n]);
        return;
    }
    __shared__ __align__(16) float plds[64][256];
    __shared__ __align__(16) float hist[64][64];
    __shared__ float gl[2][256];
    int dir = blk >> 6;
    int b   = blk & 63;
    const float* whh = dir ? whh_b : whh_f;
    const float* src = pre + ((size_t)dir * 8192 + (size_t)b * G_) * 256;
    int e = t & 63;
    int q = t >> 6;

    float4 wv[16];
#pragma unroll
    for (int c = 0; c < 16; c++) wv[c] = ((const float4*)(whh + (size_t)t * 64))[c];

    float h = 0.f, creg = 0.f;

    for (int half = 0; half < 2; half++) {
        {
            int base = (dir ^ half) ? 64 : 0;
            const float4* s4 = (const float4*)(src + (size_t)base * 256);
            float4* d4 = (float4*)&plds[0][0];
#pragma unroll
            for (int i = 0; i < 16; i++) d4[i * 256 + t] = s4[i * 256 + t];
        }
        __syncthreads();
        for (int kk = 0; kk < 64; kk++) {
            int k = half * 64 + kk;
            int srow = dir ? (63 - kk) : kk;
            float p = plds[srow][t];
            float a0 = p, a1 = 0.f, a2 = 0.f, a3 = 0.f;
#pragma unroll
            for (int c = 0; c < 16; c++) {
                float f0 = __int_as_float(__builtin_amdgcn_readlane(__float_as_int(h), 4 * c + 0));
                float f1 = __int_as_float(__builtin_amdgcn_readlane(__float_as_int(h), 4 * c + 1));
                float f2 = __int_as_float(__builtin_amdgcn_readlane(__float_as_int(h), 4 * c + 2));
                float f3 = __int_as_float(__builtin_amdgcn_readlane(__float_as_int(h), 4 * c + 3));
                a0 += wv[c].x * f0;
                a1 += wv[c].y * f1;
                a2 += wv[c].z * f2;
                a3 += wv[c].w * f3;
            }
            float g = (a0 + a1) + (a2 + a3);
            gl[k & 1][t] = (q == 2) ? tanh_fast(g) : sigm(g);
            __syncthreads();
            float ai = gl[k & 1][e];
            float af = gl[k & 1][64 + e];
            float ag = gl[k & 1][128 + e];
            float ao = gl[k & 1][192 + e];
            creg = af * creg + ai * ag;
            h = ao * tanh_fast(creg);
            if (q == 0) hist[srow][e] = h;
        }
        __syncthreads();
        int sbase = (dir ? (1 - half) : half) * 64;
#pragma unroll
        for (int i = 0; i < 16; i++) {
            int row = q * 16 + i;
            int s = sbase + row;
            hgrp[((size_t)(b * G_ + s)) * 128 + dir * 64 + e] = hist[row][e];
        }
    }
}

// ---------------- K_gp: gather + projections + BN partial stats (fused) -----
__global__ __launch_bounds__(256) void k_gp(const int* __restrict__ idx,
                                            const int* __restrict__ p2g,
                                            const float* __restrict__ hgrp,
                                            const int* __restrict__ cu,
                                            const int* __restrict__ cv,
                                            const float* __restrict__ wsrc,
                                            const float* __restrict__ bsrc,
                                            const float* __restrict__ wdst,
                                            const float* __restrict__ bdst,
                                            float* __restrict__ Ps, float* __restrict__ Pd,
                                            float* __restrict__ bn_raw) {
    __shared__ __align__(16) float hsl[8][128];
    __shared__ float red[256];
    int m0 = blockIdx.x * 8;
    int t  = threadIdx.x;
    int d = t & 127, mh = t >> 7;
#pragma unroll
    for (int rep = 0; rep < 4; rep++) {
        int ml = rep * 2 + mh;
        int m  = m0 + ml;
        int b  = m >> 5;
        float acc = 0.f;
#pragma unroll
        for (int k = 0; k < 8; k++) {
            int l = idx[m * 8 + k];
            int g = p2g[b * L_ + l];
            acc += hgrp[((size_t)b * G_ + g) * 128 + d];
        }
        hsl[ml][d] = acc;
    }
    __syncthreads();
    int ml = t >> 5, o = t & 31;
    int m  = m0 + ml;
    const float4* hp = (const float4*)&hsl[ml][0];
    float cw_u = (float)cu[m], cw_v = (float)cv[m];
#pragma unroll 1
    for (int side = 0; side < 2; side++) {
        const float* W = side ? wdst : wsrc;
        float4 wr[32];
#pragma unroll
        for (int c = 0; c < 32; c++) wr[c] = ((const float4*)(W + (size_t)o * 128))[c];
        float acc = side ? bdst[o] : bsrc[o];
#pragma unroll
        for (int c = 0; c < 32; c++) {
            float4 h4 = hp[c];
            acc += h4.x * wr[c].x + h4.y * wr[c].y + h4.z * wr[c].z + h4.w * wr[c].w;
        }
        (side ? Pd : Ps)[(size_t)m * 32 + o] = acc;
        float cw = side ? cw_v : cw_u;
        red[t] = cw * acc;
        __syncthreads();
        if (t < 32) {
            float s = 0.f;
#pragma unroll
            for (int i = 0; i < 8; i++) s += red[i * 32 + t];
            atomicAdd(&bn_raw[side * 64 + t], s);
        }
        __syncthreads();
        red[t] = cw * acc * acc;
        __syncthreads();
        if (t < 32) {
            float s = 0.f;
#pragma unroll
            for (int i = 0; i < 8; i++) s += red[i * 32 + t];
            atomicAdd(&bn_raw[side * 64 + 32 + t], s);
        }
        __syncthreads();
    }
}

// ---------------- K_prep: BN-normalize; build hsaugT[i][m] and htp (f16x2) --
__global__ __launch_bounds__(256) void k_prep(const float* __restrict__ Ps,
                                              const float* __restrict__ Pd,
                                              const float* __restrict__ bn_raw,
                                              const float* __restrict__ gs,
                                              const float* __restrict__ bes,
                                              const float* __restrict__ gd,
                                              const float* __restrict__ bed,
                                              float* __restrict__ hsaugT,
                                              v2h* __restrict__ htp) {
    int blk = blockIdx.x;
    int t   = threadIdx.x;
    constexpr float invE = 1.f / (float)E_;
    if (blk < 264) {                        // 264*256 = 33*2048
        int gid = blk * 256 + t;
        int c = gid >> 11;                   // 0..32
        int m = gid & 2047;
        float val = 1.f;
        if (c < 32) {
            float mu  = bn_raw[c] * invE;
            float isd = rsqrtf(bn_raw[32 + c] * invE - mu * mu + 1e-5f);
            val = gs[c] * (Ps[(size_t)m * 32 + c] - mu) * isd + bes[c];
        }
        hsaugT[(size_t)c * 2048 + m] = val;   // coalesced over m
        return;
    }
    int gid = (blk - 264) * 256 + t;         // 128*256 = 2048*16
    int m  = gid >> 4;
    int jp = gid & 15;
    int j0 = 2 * jp, j1 = 2 * jp + 1;
    float mu0  = bn_raw[64 + j0] * invE;
    float isd0 = rsqrtf(bn_raw[96 + j0] * invE - mu0 * mu0 + 1e-5f);
    float mu1  = bn_raw[64 + j1] * invE;
    float isd1 = rsqrtf(bn_raw[96 + j1] * invE - mu1 * mu1 + 1e-5f);
    float h0 = gd[j0] * (Pd[(size_t)m * 32 + j0] - mu0) * isd0 + bed[j0];
    float h1 = gd[j1] * (Pd[(size_t)m * 32 + j1] - mu1) * isd1 + bed[j1];
    v2h p;
    p.x = (_Float16)h0; p.y = (_Float16)h1;
    htp[gid] = p;                            // coalesced
}

// ---------------- K_agemm: 8 m per block (no spill), A f16x2 + A32 plane ----
__global__ __launch_bounds__(256) void k_agemm(const float* __restrict__ hsaugT,
                                               const float* __restrict__ waug,
                                               v2h* __restrict__ Ah,
                                               float* __restrict__ A32) {
    int mt = blockIdx.x;                   // 256 tiles of 8 m
    int jp = blockIdx.y;                   // 0..16
    int t  = threadIdx.x;                  // rh
    if (jp < 16) {
        float w0[JA], w1[JA];
#pragma unroll
        for (int i = 0; i < JA; i++) {
            w0[i] = waug[(size_t)i * COLS + (2 * jp) * 256 + t];
            w1[i] = waug[(size_t)i * COLS + (2 * jp + 1) * 256 + t];
        }
        float acc0[8], acc1[8];
#pragma unroll
        for (int ml = 0; ml < 8; ml++) { acc0[ml] = 0.f; acc1[ml] = 0.f; }
#pragma unroll 3
        for (int i = 0; i < JA; i++) {
            const float* hr = hsaugT + (size_t)i * 2048 + mt * 8;   // s_load dwordx8
#pragma unroll
            for (int ml = 0; ml < 8; ml++) {
                acc0[ml] += hr[ml] * w0[i];
                acc1[ml] += hr[ml] * w1[i];
            }
        }
#pragma unroll
        for (int ml = 0; ml < 8; ml++) {
            v2h p;
            p.x = (_Float16)acc0[ml]; p.y = (_Float16)acc1[ml];
            Ah[(size_t)(mt * 8 + ml) * 4096 + jp * 256 + t] = p;
        }
    } else {
        float w2[JA];
#pragma unroll
        for (int i = 0; i < JA; i++) w2[i] = waug[(size_t)i * COLS + 32 * 256 + t];
        float acc[8];
#pragma unroll
        for (int ml = 0; ml < 8; ml++) acc[ml] = 0.f;
#pragma unroll 3
        for (int i = 0; i < JA; i++) {
            const float* hr = hsaugT + (size_t)i * 2048 + mt * 8;
#pragma unroll
            for (int ml = 0; ml < 8; ml++) acc[ml] += hr[ml] * w2[i];
        }
#pragma unroll
        for (int ml = 0; ml < 8; ml++)
            A32[(size_t)(mt * 8 + ml) * 256 + t] = acc[ml];
    }
}

// ---------------- K_z: MFMA edge-tile GEMM + replicated LN-stat atomics -----
__global__ __launch_bounds__(256) void k_z(const unsigned int* __restrict__ Ah,
                                           const float* __restrict__ A32,
                                           const uint4* __restrict__ htp4,
                                           const int* __restrict__ ustart,
                                           const int2* __restrict__ eonv,
                                           _Float16* __restrict__ zh,
                                           float* __restrict__ zsumR,
                                           float* __restrict__ zsqR) {
    int t    = threadIdx.x;
    int lane = t & 63;
    int uu   = blockIdx.x * 4 + (t >> 6);
    int l15  = lane & 15, quad = lane >> 4;

    // B fragments for all 16 rh-tiles (64 VGPRs, loaded once per u)
    uint4 bf[16];
#pragma unroll
    for (int nt = 0; nt < 16; nt++) {
        const unsigned int* bp = Ah + (size_t)uu * 4096 + (quad * 4) * 256 + nt * 16 + l15;
        bf[nt].x = bp[0]; bf[nt].y = bp[256]; bf[nt].z = bp[512]; bf[nt].w = bp[768];
    }
    float a32[16];
#pragma unroll
    for (int nt = 0; nt < 16; nt++) a32[nt] = A32[(size_t)uu * 256 + nt * 16 + l15];

    float s1[16], s2[16];
#pragma unroll
    for (int nt = 0; nt < 16; nt++) { s1[nt] = 0.f; s2[nt] = 0.f; }

    int e0 = ustart[uu], e1 = ustart[uu + 1];
    for (int base = e0; base < e1; base += 16) {
        int ei = min(base + l15, e1 - 1);          // clamp: duplicate rows are idempotent
        int2 q = eonv[ei];
        uint4 afu = htp4[(size_t)q.y * 4 + quad];  // A-frag: vector dwordx4, no broadcast
        cvt8 ac; ac.u4 = afu;
        int nrow[4], valid[4];
#pragma unroll
        for (int r = 0; r < 4; r++) {
            int er = quad * 4 + r;
            nrow[r]  = __builtin_amdgcn_ds_bpermute(er << 2, q.x);   // n of D-row er
            valid[r] = (base + er) < e1;
        }
#pragma unroll
        for (int nt = 0; nt < 16; nt++) {
            cvt8 bc; bc.u4 = bf[nt];
            v4f acc = { a32[nt], a32[nt], a32[nt], a32[nt] };
            acc = __builtin_amdgcn_mfma_f32_16x16x32_f16(ac.h8, bc.h8, acc, 0, 0, 0);
#pragma unroll
            for (int r = 0; r < 4; r++) {
                if (valid[r]) {
                    float z = acc[r];
                    zh[(size_t)nrow[r] * 256 + nt * 16 + l15] = (_Float16)z;
                    s1[nt] += z; s2[nt] += z * z;
                }
            }
        }
    }
    int rep = (blockIdx.x & (NREP - 1)) * 256;     // replica slice (atomic decontention)
#pragma unroll
    for (int nt = 0; nt < 16; nt++) {
        float a = s1[nt], b = s2[nt];
        a += __shfl_xor(a, 16); a += __shfl_xor(a, 32);
        b += __shfl_xor(b, 16); b += __shfl_xor(b, 32);
        if (quad == 0) {
            atomicAdd(&zsumR[rep + nt * 16 + l15], a);
            atomicAdd(&zsqR[rep + nt * 16 + l15], b);
        }
    }
}

// ---------------- K_logit: LN (replica-sum inline) + tanh + contract --------
__global__ __launch_bounds__(256) void k_logit(const _Float16* __restrict__ zh,
                                               const float* __restrict__ zsumR,
                                               const float* __restrict__ zsqR,
                                               const float* __restrict__ ntlu,
                                               const float* __restrict__ ntlg,
                                               const float* __restrict__ ntlbe,
                                               float* __restrict__ out) {
    int t  = threadIdx.x;                 // rh = r*16+h
    int n0 = blockIdx.x * 16;
    float su = 0.f, sq = 0.f;
#pragma unroll
    for (int r = 0; r < NREP; r++) {
        su += zsumR[r * 256 + t];
        sq += zsqR[r * 256 + t];
    }
    float mu  = su / (float)E_;
    float var = sq / (float)E_ - mu * mu;
    float isd = rsqrtf(var + 1e-5f);
    float g   = ntlg[t],  be  = ntlbe[t];
    float uw  = ntlu[t];
    float zv[16];
#pragma unroll
    for (int nl = 0; nl < 16; nl++)
        zv[nl] = (float)zh[(size_t)(n0 + nl) * 256 + t];
#pragma unroll 1
    for (int nl = 0; nl < 16; nl++) {
        float zn  = g * (zv[nl] - mu) * isd + be;
        float val = uw * tanh_fast(zn);
        val += __shfl_xor(val, 1);
        val += __shfl_xor(val, 2);
        val += __shfl_xor(val, 4);
        val += __shfl_xor(val, 8);
        if ((t & 15) == 0) out[(size_t)(n0 + nl) * 16 + (t >> 4)] = val;
    }
}

// ============================ host side =====================================
extern "C" void kernel_launch(void* const* d_in, const int* in_sizes, int n_in,
                              void* d_out, int out_size, void* d_ws, size_t ws_size,
                              hipStream_t stream) {
    const int*   seq   = (const int*)d_in[0];
    const int*   p2g   = (const int*)d_in[1];
    const int*   idx   = (const int*)d_in[2];
    const int*   u     = (const int*)d_in[3];
    const int*   v     = (const int*)d_in[4];
    const float* emb   = (const float*)d_in[5];
    const float* wihf  = (const float*)d_in[6];
    const float* whhf  = (const float*)d_in[7];
    const float* bihf  = (const float*)d_in[8];
    const float* bhhf  = (const float*)d_in[9];
    const float* wihb  = (const float*)d_in[10];
    const float* whhb  = (const float*)d_in[11];
    const float* bihb  = (const float*)d_in[12];
    const float* bhhb  = (const float*)d_in[13];
    const float* wsrc  = (const float*)d_in[14];
    const float* bsrc  = (const float*)d_in[15];
    const float* wdst  = (const float*)d_in[16];
    const float* bdst  = (const float*)d_in[17];
    const float* gs    = (const float*)d_in[18];
    const float* bes   = (const float*)d_in[19];
    const float* gd    = (const float*)d_in[20];
    const float* bed   = (const float*)d_in[21];
    const float* ntlw  = (const float*)d_in[22];
    const float* ntlv  = (const float*)d_in[23];
    const float* ntlb  = (const float*)d_in[24];
    const float* ntlu  = (const float*)d_in[25];
    const float* ntlg  = (const float*)d_in[26];
    const float* ntlbe = (const float*)d_in[27];
    float* out = (float*)d_out;

    char* ws = (char*)d_ws;
    size_t off = 0;
    auto take = [&](size_t bytes) -> char* {
        char* p = ws + off;
        off = (off + bytes + 255) & ~(size_t)255;
        return p;
    };
    // zeroed region (contiguous, one memset)
    int*   cnt_u  = (int*)  take(2048 * 4);
    int*   cnt_v  = (int*)  take(2048 * 4);
    float* zsumR  = (float*)take((size_t)NREP * 256 * 4);
    float* zsqR   = (float*)take((size_t)NREP * 256 * 4);
    float* bn_raw = (float*)take(128 * 4);
    float* x_grp  = (float*)take((size_t)B_ * G_ * 64 * 4);   // accumulated via atomics
    size_t zero_bytes = off;
    // rest
    int*   ucursor = (int*)  take(2048 * 4);
    int*   ustart  = (int*)  take(2049 * 4);
    int2*  eonv    = (int2*) take((size_t)E_ * 8);
    float* pre     = (float*)take((size_t)2 * 8192 * 256 * 4);
    float* hgrp    = (float*)take((size_t)B_ * G_ * 128 * 4);
    float* Psrc    = (float*)take((size_t)M_ * 32 * 4);
    float* Pdst    = (float*)take((size_t)M_ * 32 * 4);
    float* hsaugT  = (float*)take((size_t)36 * 2048 * 4);
    v2h*   htp     = (v2h*)  take((size_t)M_ * 16 * 4);
    float* waug    = (float*)take((size_t)JA * COLS * 4);
    v2h*   Ah      = (v2h*)  take((size_t)M_ * 4096 * 4);
    float* A32     = (float*)take((size_t)M_ * 256 * 4);
    _Float16* zbuf = (_Float16*)take((size_t)E_ * 256 * 2);
    (void)ws_size; (void)in_sizes; (void)n_in; (void)out_size;

    hipMemsetAsync(d_ws, 0, zero_bytes, stream);

    k_eh<<<512 + 1089, 256, 0, stream>>>(seq, p2g, emb, u, v, ntlw, ntlv, ntlb,
                                         x_grp, cnt_u, cnt_v, waug);
    k_pre<<<513, 256, 0, stream>>>(x_grp, wihf, bihf, bhhf, wihb, bihb, bhhb, pre,
                                   cnt_u, ustart, ucursor);
    k_lstm<<<384, 256, 0, stream>>>(pre, whhf, whhb, hgrp, u, v, ucursor, eonv);
    k_gp<<<M_ / 8, 256, 0, stream>>>(idx, p2g, hgrp, cnt_u, cnt_v,
                                     wsrc, bsrc, wdst, bdst, Psrc, Pdst, bn_raw);
    k_prep<<<392, 256, 0, stream>>>(Psrc, Pdst, bn_raw, gs, bes, gd, bed, hsaugT, htp);
    k_agemm<<<dim3(256, 17), 256, 0, stream>>>(hsaugT, waug, Ah, A32);
    k_z<<<512, 256, 0, stream>>>((const unsigned int*)Ah, A32, (const uint4*)htp,
                                 ustart, eonv, zbuf, zsumR, zsqR);
    k_logit<<<E_ / 16, 256, 0, stream>>>(zbuf, zsumR, zsqR, ntlu, ntlg, ntlbe, out);
}

// Round 12
// 353.708 us; speedup vs baseline: 1.1496x; 1.1496x over previous
//
#include <hip/hip_runtime.h>
#include <hip/hip_bf16.h>
#include <hip/hip_fp16.h>
#include <cstdint>

// Problem constants
constexpr int B_   = 64;
constexpr int L_   = 512;
constexpr int G_   = 128;
constexpr int E_   = 65536;
constexpr int RH   = 256;    // NREL*NHID
constexpr int M_   = 2048;   // B*N distinct nodes
constexpr int JA   = 33;     // augmented j (32 + const-1 slot)
constexpr int COLS = RH * JA;   // 8448
constexpr int NREP = 16;     // LN-stat accumulator replicas (atomic decontention)

typedef _Float16 v2h __attribute__((ext_vector_type(2)));
typedef _Float16 v8h __attribute__((ext_vector_type(8)));
typedef float    v4f __attribute__((ext_vector_type(4)));
typedef union { uint4 u4; v8h h8; } cvt8;

#define DEV static __device__ __forceinline__

DEV float sigm(float x) { return 1.f / (1.f + __expf(-x)); }
DEV float tanh_fast(float x) {
    x = fminf(15.f, fmaxf(-15.f, x));
    float e = __expf(2.f * x);
    return (e - 1.f) / (e + 1.f);
}

// ---------------- K_eh: embed + edge histograms + waug build ----------------
// blocks 0..255: embed (4 blocks/batch, lgkm-clean inner loop);
// blocks 256..511: hist; 512..1600: waug (read-coalesced).
// waug layout: waug[i*COLS + j*256 + rh]
__global__ __launch_bounds__(256) void k_eh(const int* __restrict__ seq,
                                            const int* __restrict__ p2g,
                                            const float* __restrict__ emb,
                                            const int* __restrict__ u,
                                            const int* __restrict__ v,
                                            const float* __restrict__ ntlw,
                                            const float* __restrict__ ntlv,
                                            const float* __restrict__ ntlb,
                                            float* __restrict__ xg,
                                            int* __restrict__ cu, int* __restrict__ cv,
                                            float* __restrict__ waug) {
    int blk = blockIdx.x;
    int t   = threadIdx.x;
    if (blk >= 512) {
        int gid = (blk - 512) * 256 + t;      // j-fastest: coalesced ntlw reads
        int i   = gid / COLS;
        int rem = gid - i * COLS;
        int rh  = rem / JA;
        int j   = rem - rh * JA;
        float val;
        if (i < 32) val = (j < 32) ? ntlw[((size_t)rh * 32 + i) * 32 + j] : ntlv[rh * 64 + i];
        else        val = (j < 32) ? ntlv[rh * 64 + 32 + j] : ntlb[rh];
        waug[(size_t)i * COLS + j * 256 + rh] = val;   // scattered, L2-absorbed
        return;
    }
    if (blk >= 256) {
        int n = (blk - 256) * 256 + t;
        atomicAdd(&cu[u[n]], 1);
        atomicAdd(&cv[v[n]], 1);
        return;
    }
    // ---- embed: 4 blocks per batch, each covers 128 sequence positions ----
    __shared__ float xgl[G_ * 64];          // 32 KB partial sums
    __shared__ int sl[128], gld[128];
    int b = blk >> 2, part = blk & 3;
    for (int i = t; i < G_ * 64; i += 256) xgl[i] = 0.f;
    if (t < 128) {
        sl[t]  = seq[b * L_ + part * 128 + t];
        gld[t] = p2g[b * L_ + part * 128 + t];
    }
    __syncthreads();
    int d = t & 63, sub = t >> 6;
#pragma unroll
    for (int gg = 0; gg < 2; gg++) {
        int sv[16], gv[16];
#pragma unroll
        for (int k = 0; k < 16; k++) {       // batch LDS reads first (lgkm group)
            sv[k] = sl[sub * 32 + gg * 16 + k];
            gv[k] = gld[sub * 32 + gg * 16 + k];
        }
#pragma unroll
        for (int k = 0; k < 16; k++)         // then pure-vm loads + ds atomics
            atomicAdd(&xgl[gv[k] * 64 + d], emb[(size_t)sv[k] * 64 + d]);
    }
    __syncthreads();
    for (int i = t; i < G_ * 64; i += 256)   // flush partials (xg pre-zeroed)
        atomicAdd(&xg[(size_t)b * G_ * 64 + i], xgl[i]);
}

// ---------------- K_pre: input-gate GEMM (scalar x broadcast) + scan --------
__global__ __launch_bounds__(256) void k_pre(const float* __restrict__ xg,
                                             const float* __restrict__ wihf,
                                             const float* __restrict__ bihf,
                                             const float* __restrict__ bhhf,
                                             const float* __restrict__ wihb,
                                             const float* __restrict__ bihb,
                                             const float* __restrict__ bhhb,
                                             float* __restrict__ pre,
                                             const int* __restrict__ cu,
                                             int* __restrict__ ustart,
                                             int* __restrict__ ucursor) {
    int blk = blockIdx.x;
    int t   = threadIdx.x;
    if (blk == 512) {
        __shared__ int ps[256];
        int base = t * 8, run = 0;
        int c[8], loc[8];
#pragma unroll
        for (int i = 0; i < 8; i++) c[i] = cu[base + i];
#pragma unroll
        for (int i = 0; i < 8; i++) { loc[i] = run; run += c[i]; }
        ps[t] = run;
        __syncthreads();
        for (int off = 1; off < 256; off <<= 1) {
            int a = (t >= off) ? ps[t - off] : 0;
            __syncthreads();
            ps[t] += a;
            __syncthreads();
        }
        int ex = ps[t] - run;
#pragma unroll
        for (int i = 0; i < 8; i++) { ustart[base + i] = ex + loc[i]; ucursor[base + i] = ex + loc[i]; }
        if (t == 255) ustart[2048] = E_;
        return;
    }
    int dir = blk >> 8;
    const float* wih = dir ? wihb : wihf;
    float bias = dir ? (bihb[t] + bhhb[t]) : (bihf[t] + bhhf[t]);
    int r0 = (blk & 255) * 32;

    float4 wv[16];
#pragma unroll
    for (int c = 0; c < 16; c++) wv[c] = ((const float4*)(wih + t * 64))[c];

#pragma unroll 2
    for (int ml = 0; ml < 32; ml++) {
        const float* xr = xg + (size_t)(r0 + ml) * 64;   // wave-uniform -> s_load
        float acc = bias;
#pragma unroll
        for (int c = 0; c < 16; c++) {
            float x0 = xr[4 * c], x1 = xr[4 * c + 1], x2 = xr[4 * c + 2], x3 = xr[4 * c + 3];
            acc += x0 * wv[c].x + x1 * wv[c].y + x2 * wv[c].z + x3 * wv[c].w;
        }
        pre[((size_t)dir * 8192 + r0 + ml) * 256 + t] = acc;   // gate-major, coalesced
    }
}

// ---------------- K_lstm: merged 128-step recurrence --------- --------------
// blocks 128..383: edge counting-sort rider.
__global__ __launch_bounds__(256, 1) void k_lstm(const float* __restrict__ pre,
                                                 const float* __restrict__ whh_f,
                                                 const float* __restrict__ whh_b,
                                                 float* __restrict__ hgrp,
                                                 const int* __restrict__ u,
                                                 const int* __restrict__ v,
                                                 int* __restrict__ ucursor,
                                                 int2* __restrict__ eonv) {
    int blk = blockIdx.x;
    int t   = threadIdx.x;
    if (blk >= 128) {
        int n = (blk - 128) * 256 + t;
        int pos = atomicAdd(&ucursor[u[n]], 1);
        eonv[pos] = make_int2(n, v[n]);
        return;
    }
    __shared__ __align__(16) float plds[64][256];
    __shared__ __align__(16) float hist[64][64];
    __shared__ float gl[2][256];
    int dir = blk >> 6;
    int b   = blk & 63;
    const float* whh = dir ? whh_b : whh_f;
    const float* src = pre + ((size_t)dir * 8192 + (size_t)b * G_) * 256;
    int e = t & 63;
    int q = t >> 6;

    float4 wv[16];
#pragma unroll
    for (int c = 0; c < 16; c++) wv[c] = ((const float4*)(whh + (size_t)t * 64))[c];

    float h = 0.f, creg = 0.f;

    for (int half = 0; half < 2; half++) {
        {
            int base = (dir ^ half) ? 64 : 0;
            const float4* s4 = (const float4*)(src + (size_t)base * 256);
            float4* d4 = (float4*)&plds[0][0];
#pragma unroll
            for (int i = 0; i < 16; i++) d4[i * 256 + t] = s4[i * 256 + t];
        }
        __syncthreads();
        for (int kk = 0; kk < 64; kk++) {
            int k = half * 64 + kk;
            int srow = dir ? (63 - kk) : kk;
            float p = plds[srow][t];
            float a0 = p, a1 = 0.f, a2 = 0.f, a3 = 0.f;
#pragma unroll
            for (int c = 0; c < 16; c++) {
                float f0 = __int_as_float(__builtin_amdgcn_readlane(__float_as_int(h), 4 * c + 0));
                float f1 = __int_as_float(__builtin_amdgcn_readlane(__float_as_int(h), 4 * c + 1));
                float f2 = __int_as_float(__builtin_amdgcn_readlane(__float_as_int(h), 4 * c + 2));
                float f3 = __int_as_float(__builtin_amdgcn_readlane(__float_as_int(h), 4 * c + 3));
                a0 += wv[c].x * f0;
                a1 += wv[c].y * f1;
                a2 += wv[c].z * f2;
                a3 += wv[c].w * f3;
            }
            float g = (a0 + a1) + (a2 + a3);
            gl[k & 1][t] = (q == 2) ? tanh_fast(g) : sigm(g);
            __syncthreads();
            float ai = gl[k & 1][e];
            float af = gl[k & 1][64 + e];
            float ag = gl[k & 1][128 + e];
            float ao = gl[k & 1][192 + e];
            creg = af * creg + ai * ag;
            h = ao * tanh_fast(creg);
            if (q == 0) hist[srow][e] = h;
        }
        __syncthreads();
        int sbase = (dir ? (1 - half) : half) * 64;
#pragma unroll
        for (int i = 0; i < 16; i++) {
            int row = q * 16 + i;
            int s = sbase + row;
            hgrp[((size_t)(b * G_ + s)) * 128 + dir * 64 + e] = hist[row][e];
        }
    }
}

// ---------------- K_gp: gather + projections + BN partial stats (fused) -----
__global__ __launch_bounds__(256) void k_gp(const int* __restrict__ idx,
                                            const int* __restrict__ p2g,
                                            const float* __restrict__ hgrp,
                                            const int* __restrict__ cu,
                                            const int* __restrict__ cv,
                                            const float* __restrict__ wsrc,
                                            const float* __restrict__ bsrc,
                                            const float* __restrict__ wdst,
                                            const float* __restrict__ bdst,
                                            float* __restrict__ Ps, float* __restrict__ Pd,
                                            float* __restrict__ bn_raw) {
    __shared__ __align__(16) float hsl[8][128];
    __shared__ float red[256];
    int m0 = blockIdx.x * 8;
    int t  = threadIdx.x;
    int d = t & 127, mh = t >> 7;
#pragma unroll
    for (int rep = 0; rep < 4; rep++) {
        int ml = rep * 2 + mh;
        int m  = m0 + ml;
        int b  = m >> 5;
        float acc = 0.f;
#pragma unroll
        for (int k = 0; k < 8; k++) {
            int l = idx[m * 8 + k];
            int g = p2g[b * L_ + l];
            acc += hgrp[((size_t)b * G_ + g) * 128 + d];
        }
        hsl[ml][d] = acc;
    }
    __syncthreads();
    int ml = t >> 5, o = t & 31;
    int m  = m0 + ml;
    const float4* hp = (const float4*)&hsl[ml][0];
    float cw_u = (float)cu[m], cw_v = (float)cv[m];
#pragma unroll 1
    for (int side = 0; side < 2; side++) {
        const float* W = side ? wdst : wsrc;
        float4 wr[32];
#pragma unroll
        for (int c = 0; c < 32; c++) wr[c] = ((const float4*)(W + (size_t)o * 128))[c];
        float acc = side ? bdst[o] : bsrc[o];
#pragma unroll
        for (int c = 0; c < 32; c++) {
            float4 h4 = hp[c];
            acc += h4.x * wr[c].x + h4.y * wr[c].y + h4.z * wr[c].z + h4.w * wr[c].w;
        }
        (side ? Pd : Ps)[(size_t)m * 32 + o] = acc;
        float cw = side ? cw_v : cw_u;
        red[t] = cw * acc;
        __syncthreads();
        if (t < 32) {
            float s = 0.f;
#pragma unroll
            for (int i = 0; i < 8; i++) s += red[i * 32 + t];
            atomicAdd(&bn_raw[side * 64 + t], s);
        }
        __syncthreads();
        red[t] = cw * acc * acc;
        __syncthreads();
        if (t < 32) {
            float s = 0.f;
#pragma unroll
            for (int i = 0; i < 8; i++) s += red[i * 32 + t];
            atomicAdd(&bn_raw[side * 64 + 32 + t], s);
        }
        __syncthreads();
    }
}

// ---------------- K_prep: BN-normalize; build hsaugT[i][m] and htp (f16x2) --
__global__ __launch_bounds__(256) void k_prep(const float* __restrict__ Ps,
                                              const float* __restrict__ Pd,
                                              const float* __restrict__ bn_raw,
                                              const float* __restrict__ gs,
                                              const float* __restrict__ bes,
                                              const float* __restrict__ gd,
                                              const float* __restrict__ bed,
                                              float* __restrict__ hsaugT,
                                              v2h* __restrict__ htp) {
    int blk = blockIdx.x;
    int t   = threadIdx.x;
    constexpr float invE = 1.f / (float)E_;
    if (blk < 264) {                        // 264*256 = 33*2048
        int gid = blk * 256 + t;
        int c = gid >> 11;                   // 0..32
        int m = gid & 2047;
        float val = 1.f;
        if (c < 32) {
            float mu  = bn_raw[c] * invE;
            float isd = rsqrtf(bn_raw[32 + c] * invE - mu * mu + 1e-5f);
            val = gs[c] * (Ps[(size_t)m * 32 + c] - mu) * isd + bes[c];
        }
        hsaugT[(size_t)c * 2048 + m] = val;   // coalesced over m
        return;
    }
    int gid = (blk - 264) * 256 + t;         // 128*256 = 2048*16
    int m  = gid >> 4;
    int jp = gid & 15;
    int j0 = 2 * jp, j1 = 2 * jp + 1;
    float mu0  = bn_raw[64 + j0] * invE;
    float isd0 = rsqrtf(bn_raw[96 + j0] * invE - mu0 * mu0 + 1e-5f);
    float mu1  = bn_raw[64 + j1] * invE;
    float isd1 = rsqrtf(bn_raw[96 + j1] * invE - mu1 * mu1 + 1e-5f);
    float h0 = gd[j0] * (Pd[(size_t)m * 32 + j0] - mu0) * isd0 + bed[j0];
    float h1 = gd[j1] * (Pd[(size_t)m * 32 + j1] - mu1) * isd1 + bed[j1];
    v2h p;
    p.x = (_Float16)h0; p.y = (_Float16)h1;
    htp[gid] = p;                            // coalesced
}

// ---------------- K_agemm: w in REGISTERS (fully-unrolled i), low block count
// grid (16 m-slices, 17 jp). Each block: load w once, loop 16 chunks x 8 m.
__global__ __launch_bounds__(256, 1) void k_agemm(const float* __restrict__ hsaugT,
                                                  const float* __restrict__ waug,
                                                  v2h* __restrict__ Ah,
                                                  float* __restrict__ A32) {
    int ms = blockIdx.x;                   // 16 slices of 128 m
    int jp = blockIdx.y;                   // 0..16
    int t  = threadIdx.x;                  // rh
    int mbase = ms * 128;
    if (jp < 16) {
        float w0[JA], w1[JA];
#pragma unroll
        for (int i = 0; i < JA; i++) {      // FULL unroll: static indices -> registers
            w0[i] = waug[(size_t)i * COLS + (2 * jp) * 256 + t];
            w1[i] = waug[(size_t)i * COLS + (2 * jp + 1) * 256 + t];
        }
#pragma unroll 1
        for (int ch = 0; ch < 16; ch++) {
            int m0 = mbase + ch * 8;
            float acc0[8], acc1[8];
#pragma unroll
            for (int ml = 0; ml < 8; ml++) { acc0[ml] = 0.f; acc1[ml] = 0.f; }
#pragma unroll
            for (int i = 0; i < JA; i++) {
                const float* hr = hsaugT + (size_t)i * 2048 + m0;   // s_load dwordx8
#pragma unroll
                for (int ml = 0; ml < 8; ml++) {
                    float hv = hr[ml];
                    acc0[ml] += hv * w0[i];
                    acc1[ml] += hv * w1[i];
                }
            }
#pragma unroll
            for (int ml = 0; ml < 8; ml++) {
                v2h p;
                p.x = (_Float16)acc0[ml]; p.y = (_Float16)acc1[ml];
                Ah[(size_t)(m0 + ml) * 4096 + jp * 256 + t] = p;
            }
        }
    } else {
        float w2[JA];
#pragma unroll
        for (int i = 0; i < JA; i++) w2[i] = waug[(size_t)i * COLS + 32 * 256 + t];
#pragma unroll 1
        for (int ch = 0; ch < 16; ch++) {
            int m0 = mbase + ch * 8;
            float acc[8];
#pragma unroll
            for (int ml = 0; ml < 8; ml++) acc[ml] = 0.f;
#pragma unroll
            for (int i = 0; i < JA; i++) {
                const float* hr = hsaugT + (size_t)i * 2048 + m0;
#pragma unroll
                for (int ml = 0; ml < 8; ml++) acc[ml] += hr[ml] * w2[i];
            }
#pragma unroll
            for (int ml = 0; ml < 8; ml++)
                A32[(size_t)(m0 + ml) * 256 + t] = acc[ml];
        }
    }
}

// ---------------- K_z: MFMA edge-tile GEMM + replicated LN-stat atomics -----
__global__ __launch_bounds__(256) void k_z(const unsigned int* __restrict__ Ah,
                                           const float* __restrict__ A32,
                                           const uint4* __restrict__ htp4,
                                           const int* __restrict__ ustart,
                                           const int2* __restrict__ eonv,
                                           _Float16* __restrict__ zh,
                                           float* __restrict__ zsumR,
                                           float* __restrict__ zsqR) {
    int t    = threadIdx.x;
    int lane = t & 63;
    int uu   = blockIdx.x * 4 + (t >> 6);
    int l15  = lane & 15, quad = lane >> 4;

    // B fragments for all 16 rh-tiles (64 VGPRs, loaded once per u)
    uint4 bf[16];
#pragma unroll
    for (int nt = 0; nt < 16; nt++) {
        const unsigned int* bp = Ah + (size_t)uu * 4096 + (quad * 4) * 256 + nt * 16 + l15;
        bf[nt].x = bp[0]; bf[nt].y = bp[256]; bf[nt].z = bp[512]; bf[nt].w = bp[768];
    }
    float a32[16];
#pragma unroll
    for (int nt = 0; nt < 16; nt++) a32[nt] = A32[(size_t)uu * 256 + nt * 16 + l15];

    float s1[16], s2[16];
#pragma unroll
    for (int nt = 0; nt < 16; nt++) { s1[nt] = 0.f; s2[nt] = 0.f; }

    int e0 = ustart[uu], e1 = ustart[uu + 1];
    for (int base = e0; base < e1; base += 16) {
        int ei = min(base + l15, e1 - 1);          // clamp: duplicate rows are idempotent
        int2 q = eonv[ei];
        uint4 afu = htp4[(size_t)q.y * 4 + quad];  // A-frag: vector dwordx4, no broadcast
        cvt8 ac; ac.u4 = afu;
        int nrow[4], valid[4];
#pragma unroll
        for (int r = 0; r < 4; r++) {
            int er = quad * 4 + r;
            nrow[r]  = __builtin_amdgcn_ds_bpermute(er << 2, q.x);   // n of D-row er
            valid[r] = (base + er) < e1;
        }
#pragma unroll
        for (int nt = 0; nt < 16; nt++) {
            cvt8 bc; bc.u4 = bf[nt];
            v4f acc = { a32[nt], a32[nt], a32[nt], a32[nt] };
            acc = __builtin_amdgcn_mfma_f32_16x16x32_f16(ac.h8, bc.h8, acc, 0, 0, 0);
#pragma unroll
            for (int r = 0; r < 4; r++) {
                if (valid[r]) {
                    float z = acc[r];
                    zh[(size_t)nrow[r] * 256 + nt * 16 + l15] = (_Float16)z;
                    s1[nt] += z; s2[nt] += z * z;
                }
            }
        }
    }
    int rep = (blockIdx.x & (NREP - 1)) * 256;     // replica slice (atomic decontention)
#pragma unroll
    for (int nt = 0; nt < 16; nt++) {
        float a = s1[nt], b = s2[nt];
        a += __shfl_xor(a, 16); a += __shfl_xor(a, 32);
        b += __shfl_xor(b, 16); b += __shfl_xor(b, 32);
        if (quad == 0) {
            atomicAdd(&zsumR[rep + nt * 16 + l15], a);
            atomicAdd(&zsqR[rep + nt * 16 + l15], b);
        }
    }
}

// ---------------- K_logit: LN (replica-sum inline) + tanh + contract --------
__global__ __launch_bounds__(256) void k_logit(const _Float16* __restrict__ zh,
                                               const float* __restrict__ zsumR,
                                               const float* __restrict__ zsqR,
                                               const float* __restrict__ ntlu,
                                               const float* __restrict__ ntlg,
                                               const float* __restrict__ ntlbe,
                                               float* __restrict__ out) {
    int t  = threadIdx.x;                 // rh = r*16+h
    int n0 = blockIdx.x * 16;
    float su = 0.f, sq = 0.f;
#pragma unroll
    for (int r = 0; r < NREP; r++) {
        su += zsumR[r * 256 + t];
        sq += zsqR[r * 256 + t];
    }
    float mu  = su / (float)E_;
    float var = sq / (float)E_ - mu * mu;
    float isd = rsqrtf(var + 1e-5f);
    float g   = ntlg[t],  be  = ntlbe[t];
    float uw  = ntlu[t];
    float zv[16];
#pragma unroll
    for (int nl = 0; nl < 16; nl++)
        zv[nl] = (float)zh[(size_t)(n0 + nl) * 256 + t];
#pragma unroll 1
    for (int nl = 0; nl < 16; nl++) {
        float zn  = g * (zv[nl] - mu) * isd + be;
        float val = uw * tanh_fast(zn);
        val += __shfl_xor(val, 1);
        val += __shfl_xor(val, 2);
        val += __shfl_xor(val, 4);
        val += __shfl_xor(val, 8);
        if ((t & 15) == 0) out[(size_t)(n0 + nl) * 16 + (t >> 4)] = val;
    }
}

// ============================ host side =====================================
extern "C" void kernel_launch(void* const* d_in, const int* in_sizes, int n_in,
                              void* d_out, int out_size, void* d_ws, size_t ws_size,
                              hipStream_t stream) {
    const int*   seq   = (const int*)d_in[0];
    const int*   p2g   = (const int*)d_in[1];
    const int*   idx   = (const int*)d_in[2];
    const int*   u     = (const int*)d_in[3];
    const int*   v     = (const int*)d_in[4];
    const float* emb   = (const float*)d_in[5];
    const float* wihf  = (const float*)d_in[6];
    const float* whhf  = (const float*)d_in[7];
    const float* bihf  = (const float*)d_in[8];
    const float* bhhf  = (const float*)d_in[9];
    const float* wihb  = (const float*)d_in[10];
    const float* whhb  = (const float*)d_in[11];
    const float* bihb  = (const float*)d_in[12];
    const float* bhhb  = (const float*)d_in[13];
    const float* wsrc  = (const float*)d_in[14];
    const float* bsrc  = (const float*)d_in[15];
    const float* wdst  = (const float*)d_in[16];
    const float* bdst  = (const float*)d_in[17];
    const float* gs    = (const float*)d_in[18];
    const float* bes   = (const float*)d_in[19];
    const float* gd    = (const float*)d_in[20];
    const float* bed   = (const float*)d_in[21];
    const float* ntlw  = (const float*)d_in[22];
    const float* ntlv  = (const float*)d_in[23];
    const float* ntlb  = (const float*)d_in[24];
    const float* ntlu  = (const float*)d_in[25];
    const float* ntlg  = (const float*)d_in[26];
    const float* ntlbe = (const float*)d_in[27];
    float* out = (float*)d_out;

    char* ws = (char*)d_ws;
    size_t off = 0;
    auto take = [&](size_t bytes) -> char* {
        char* p = ws + off;
        off = (off + bytes + 255) & ~(size_t)255;
        return p;
    };
    // zeroed region (contiguous, one memset)
    int*   cnt_u  = (int*)  take(2048 * 4);
    int*   cnt_v  = (int*)  take(2048 * 4);
    float* zsumR  = (float*)take((size_t)NREP * 256 * 4);
    float* zsqR   = (float*)take((size_t)NREP * 256 * 4);
    float* bn_raw = (float*)take(128 * 4);
    float* x_grp  = (float*)take((size_t)B_ * G_ * 64 * 4);   // accumulated via atomics
    size_t zero_bytes = off;
    // rest
    int*   ucursor = (int*)  take(2048 * 4);
    int*   ustart  = (int*)  take(2049 * 4);
    int2*  eonv    = (int2*) take((size_t)E_ * 8);
    float* pre     = (float*)take((size_t)2 * 8192 * 256 * 4);
    float* hgrp    = (float*)take((size_t)B_ * G_ * 128 * 4);
    float* Psrc    = (float*)take((size_t)M_ * 32 * 4);
    float* Pdst    = (float*)take((size_t)M_ * 32 * 4);
    float* hsaugT  = (float*)take((size_t)36 * 2048 * 4);
    v2h*   htp     = (v2h*)  take((size_t)M_ * 16 * 4);
    float* waug    = (float*)take((size_t)JA * COLS * 4);
    v2h*   Ah      = (v2h*)  take((size_t)M_ * 4096 * 4);
    float* A32     = (float*)take((size_t)M_ * 256 * 4);
    _Float16* zbuf = (_Float16*)take((size_t)E_ * 256 * 2);
    (void)ws_size; (void)in_sizes; (void)n_in; (void)out_size;

    hipMemsetAsync(d_ws, 0, zero_bytes, stream);

    k_eh<<<512 + 1089, 256, 0, stream>>>(seq, p2g, emb, u, v, ntlw, ntlv, ntlb,
                                         x_grp, cnt_u, cnt_v, waug);
    k_pre<<<513, 256, 0, stream>>>(x_grp, wihf, bihf, bhhf, wihb, bihb, bhhb, pre,
                                   cnt_u, ustart, ucursor);
    k_lstm<<<384, 256, 0, stream>>>(pre, whhf, whhb, hgrp, u, v, ucursor, eonv);
    k_gp<<<M_ / 8, 256, 0, stream>>>(idx, p2g, hgrp, cnt_u, cnt_v,
                                     wsrc, bsrc, wdst, bdst, Psrc, Pdst, bn_raw);
    k_prep<<<392, 256, 0, stream>>>(Psrc, Pdst, bn_raw, gs, bes, gd, bed, hsaugT, htp);
    k_agemm<<<dim3(16, 17), 256, 0, stream>>>(hsaugT, waug, Ah, A32);
    k_z<<<512, 256, 0, stream>>>((const unsigned int*)Ah, A32, (const uint4*)htp,
                                 ustart, eonv, zbuf, zsumR, zsqR);
    k_logit<<<E_ / 16, 256, 0, stream>>>(zbuf, zsumR, zsqR, ntlu, ntlg, ntlbe, out);
}